// Round 6
// baseline (194.554 us; speedup 1.0000x reference)
//
#include <hip/hip_runtime.h>

// MSDeformAttn: B=2, LQ=LV=11109, D=256, NH=8, HD=32, NL=3, NP=4
// shapes: (92,92),(46,46),(23,23); starts: 0, 8464, 10580
#define LQn   11109
#define MTOT  22218   // B * LQ

typedef __attribute__((ext_vector_type(8))) short short8;
typedef __attribute__((ext_vector_type(4))) float f32x4;

__device__ __forceinline__ unsigned short f2bf(float f) {
  union { float f; unsigned int u; } v; v.f = f;
  unsigned int r = v.u + 0x7fffu + ((v.u >> 16) & 1u);  // RNE
  return (unsigned short)(r >> 16);
}

// ---------------- weight prep: transpose to (N x K) bf16, concat biases ----------------
__global__ __launch_bounds__(256) void prep_weights(
    const float* __restrict__ Wval, const float* __restrict__ Woff,
    const float* __restrict__ Wattn, const float* __restrict__ Wout,
    const float* __restrict__ boff, const float* __restrict__ battn,
    unsigned short* __restrict__ Wval_t, unsigned short* __restrict__ Wcat_t,
    unsigned short* __restrict__ Wout_t, float* __restrict__ bcat) {
  int i = blockIdx.x * 256 + threadIdx.x;   // grid = 288 blocks -> i < 73728
  int n = i >> 8, k = i & 255;              // Wt[n][k] = W[k][n]
  if (n < 256) {
    Wval_t[i] = f2bf(Wval[k * 256 + n]);
    Wout_t[i] = f2bf(Wout[k * 256 + n]);
  }
  float src = (n < 192) ? Woff[k * 192 + n] : Wattn[k * 96 + (n - 192)];
  Wcat_t[i] = f2bf(src);
  if (i < 288) bcat[i] = (i < 192) ? boff[i] : battn[i - 192];
}

// ---------------- fused GEMM1+GEMM2, A-resident ----------------
// grid = (348, 2). y=0: A=value (fp32), N=256, bf16 head-major out, 4 N-tiles.
//                  y=1: A=query (fp32), N=288, fp32 logits out, 5 N-tiles.
// A tile (64 x 256) staged to LDS once (bf16, +8 ushort row pad), reused
// across all N-tiles -> A HBM traffic 204 MB -> 45 MB.
__global__ __launch_bounds__(256) void gemm_fused12b(
    const float* __restrict__ Aval, const float* __restrict__ Aq,
    const unsigned short* __restrict__ Bval, const unsigned short* __restrict__ Bcat,
    const float* __restrict__ bval, const float* __restrict__ bcat,
    unsigned short* __restrict__ value16,     // [b][h][pix][32] bf16
    float* __restrict__ logits) {             // (M,288) fp32
  __shared__ unsigned short As[64][264];  // 528B row stride: 4-bank shift/row
  __shared__ unsigned short Bs[64][40];

  const int bm = blockIdx.x;
  const bool is2 = blockIdx.y != 0;
  const float* __restrict__ A = is2 ? Aq : Aval;
  const unsigned short* __restrict__ Bt = is2 ? Bcat : Bval;
  const float* __restrict__ bias = is2 ? bcat : bval;
  const int N = is2 ? 288 : 256;
  const int NT = is2 ? 5 : 4;

  const int t = threadIdx.x;
  const int wave = t >> 6, lane = t & 63;
  const int wm = wave >> 1, wn = wave & 1;
  const int quad = lane >> 4, l16 = lane & 15;
  const int ldr = t >> 2;          // 0..63
  const int ldk = (t & 3) * 8;     // 0/8/16/24
  const int arow = bm * 64 + ldr;

  // stage full-K A tile, fp32 -> bf16
#pragma unroll
  for (int kb = 0; kb < 8; kb++) {
    const int c0 = kb * 32 + ldk;
    float4 a0 = {0.f, 0.f, 0.f, 0.f}, a1 = a0;
    if (arow < MTOT) {
      a0 = *(const float4*)(A + (size_t)arow * 256 + c0);
      a1 = *(const float4*)(A + (size_t)arow * 256 + c0 + 4);
    }
    ushort4 lo, hi;
    lo.x = f2bf(a0.x); lo.y = f2bf(a0.y); lo.z = f2bf(a0.z); lo.w = f2bf(a0.w);
    hi.x = f2bf(a1.x); hi.y = f2bf(a1.y); hi.z = f2bf(a1.z); hi.w = f2bf(a1.w);
    *(ushort4*)(&As[ldr][c0]) = lo;
    *(ushort4*)(&As[ldr][c0 + 4]) = hi;
  }

  for (int bn = 0; bn < NT; bn++) {
    const int brow = bn * 64 + ldr;
    f32x4 acc[2][2];
    for (int i = 0; i < 2; i++)
      for (int j = 0; j < 2; j++) acc[i][j] = (f32x4){0.f, 0.f, 0.f, 0.f};

    for (int kb = 0; kb < 8; kb++) {
      uint4 bv = {0u, 0u, 0u, 0u};
      if (brow < N) bv = *(const uint4*)(Bt + (size_t)brow * 256 + kb * 32 + ldk);
      __syncthreads();                 // prev kb's Bs readers done (also covers As stage)
      *(uint4*)(&Bs[ldr][ldk]) = bv;
      __syncthreads();
      short8 af[2], bfr[2];
#pragma unroll
      for (int i = 0; i < 2; i++)
        af[i] = *(const short8*)(&As[wm * 32 + i * 16 + l16][kb * 32 + quad * 8]);
#pragma unroll
      for (int j = 0; j < 2; j++)
        bfr[j] = *(const short8*)(&Bs[wn * 32 + j * 16 + l16][quad * 8]);
#pragma unroll
      for (int i = 0; i < 2; i++)
#pragma unroll
        for (int j = 0; j < 2; j++)
          acc[i][j] = __builtin_amdgcn_mfma_f32_16x16x32_bf16(af[i], bfr[j], acc[i][j], 0, 0, 0);
    }

    // epilogue for this N-tile
#pragma unroll
    for (int i = 0; i < 2; i++)
#pragma unroll
      for (int j = 0; j < 2; j++) {
        int colg = bn * 64 + wn * 32 + j * 16 + l16;
        if (colg >= N) continue;
        float bsv = bias[colg];
        int row0 = bm * 64 + wm * 32 + i * 16 + quad * 4;
        for (int r = 0; r < 4; r++) {
          int rg = row0 + r;
          if (rg >= MTOT) continue;
          float v = acc[i][j][r] + bsv;
          if (is2) {
            logits[(size_t)rg * 288 + colg] = v;
          } else {
            int b = (rg >= LQn) ? 1 : 0;
            int p = rg - b * LQn;
            value16[((size_t)(b * 8 + (colg >> 5)) * LQn + p) * 32 + (colg & 31)] = f2bf(v);
          }
        }
      }
  }
}

// ---------------- GEMM3: A bf16 resident, out fp32 (out proj) ----------------
// grid = (348). A tile staged once, 4 N-tiles looped.
__global__ __launch_bounds__(256) void gemm_a16b(
    const unsigned short* __restrict__ A,   // (M,256) bf16
    const unsigned short* __restrict__ Bt,  // (256,256) bf16 N-major
    const float* __restrict__ bias,
    float* __restrict__ C) {                // (M,256) fp32
  __shared__ unsigned short As[64][264];
  __shared__ unsigned short Bs[64][40];

  const int t = threadIdx.x;
  const int bm = blockIdx.x;
  const int wave = t >> 6, lane = t & 63;
  const int wm = wave >> 1, wn = wave & 1;
  const int quad = lane >> 4, l16 = lane & 15;
  const int ldr = t >> 2;
  const int ldk = (t & 3) * 8;
  const int arow = bm * 64 + ldr;

#pragma unroll
  for (int kb = 0; kb < 8; kb++) {
    uint4 av = {0u, 0u, 0u, 0u};
    if (arow < MTOT) av = *(const uint4*)(A + (size_t)arow * 256 + kb * 32 + ldk);
    *(uint4*)(&As[ldr][kb * 32 + ldk]) = av;
  }

  for (int bn = 0; bn < 4; bn++) {
    const int brow = bn * 64 + ldr;
    f32x4 acc[2][2];
    for (int i = 0; i < 2; i++)
      for (int j = 0; j < 2; j++) acc[i][j] = (f32x4){0.f, 0.f, 0.f, 0.f};

    for (int kb = 0; kb < 8; kb++) {
      uint4 bv = *(const uint4*)(Bt + (size_t)brow * 256 + kb * 32 + ldk);
      __syncthreads();
      *(uint4*)(&Bs[ldr][ldk]) = bv;
      __syncthreads();
      short8 af[2], bfr[2];
#pragma unroll
      for (int i = 0; i < 2; i++)
        af[i] = *(const short8*)(&As[wm * 32 + i * 16 + l16][kb * 32 + quad * 8]);
#pragma unroll
      for (int j = 0; j < 2; j++)
        bfr[j] = *(const short8*)(&Bs[wn * 32 + j * 16 + l16][quad * 8]);
#pragma unroll
      for (int i = 0; i < 2; i++)
#pragma unroll
        for (int j = 0; j < 2; j++)
          acc[i][j] = __builtin_amdgcn_mfma_f32_16x16x32_bf16(af[i], bfr[j], acc[i][j], 0, 0, 0);
    }

#pragma unroll
    for (int i = 0; i < 2; i++)
#pragma unroll
      for (int j = 0; j < 2; j++) {
        int colg = bn * 64 + wn * 32 + j * 16 + l16;
        float bsv = bias[colg];
        int row0 = bm * 64 + wm * 32 + i * 16 + quad * 4;
        for (int r = 0; r < 4; r++) {
          int rg = row0 + r;
          if (rg < MTOT) C[(size_t)rg * 256 + colg] = acc[i][j][r] + bsv;
        }
      }
  }
}

// ---------------- sampling + softmax + weighted sum, v5 ----------------
// v4 + conflict-free phase-B: task index IS the slot (h = s&7, pl = s>>3),
// so consecutive lanes write consecutive 16B tw / 8B ti -> no bank conflicts.
__global__ __launch_bounds__(256) void msda_sample5(
    const unsigned short* __restrict__ value16,  // [b][h][pix][32] bf16
    const float* __restrict__ logits,            // (M,288)
    const float* __restrict__ refp,              // (M,3,2) (y,x)
    unsigned short* __restrict__ sampled) {      // (M,256) bf16
  __shared__ float          tw[8][96][4];   // 12.3 KB
  __shared__ unsigned short ti[8][96][4];   // 6.1 KB
  __shared__ float hmx[8][8], hrd[8][8];
  __shared__ float rfs[8][6];

  const int t = threadIdx.x;
  const int qbase = blockIdx.x * 8;

  if (t < 48) {
    int q = t / 6;
    if (qbase + q < MTOT) rfs[q][t - q * 6] = refp[(size_t)qbase * 6 + t];
  }
  if (t >= 64 && t < 128) {
    int tt = t - 64;
    int q = tt >> 3, h = tt & 7;
    int bq = qbase + q;
    if (bq < MTOT) {
      const float* lrow = logits + (size_t)bq * 288 + 192 + h * 12;
      float mx = -1e30f;
#pragma unroll
      for (int i = 0; i < 12; i++) mx = fmaxf(mx, lrow[i]);
      float den = 0.f;
#pragma unroll
      for (int i = 0; i < 12; i++) den += __expf(lrow[i] - mx);
      hmx[q][h] = mx;
      hrd[q][h] = 1.0f / den;
    }
  }
  __syncthreads();

  // build tables: 8q x 96 slots = 768 tasks; task id == (q, slot)
  {
    const int Hs[3] = {92, 46, 23};
    const int Ss[3] = {0, 8464, 10580};
#pragma unroll
    for (int r = 0; r < 3; r++) {
      const int task = t + r * 256;
      const int q = task / 96, s = task - q * 96;   // s = slot = pl*8 + h
      const int bq = qbase + q;
      if (bq < MTOT) {
        const int h = s & 7, pl = s >> 3;
        const int l = pl >> 2;
        const int H = Hs[l], W = Hs[l], S = Ss[l];
        const int ob = h * 12 + pl;                 // logit index
        const float* lrow = logits + (size_t)bq * 288;
        const float aw = __expf(lrow[192 + ob] - hmx[q][h]) * hrd[q][h];
        const float offy = lrow[2 * ob], offx = lrow[2 * ob + 1];
        const float x = rfs[q][l * 2 + 1] * W + offx - 0.5f;
        const float y = rfs[q][l * 2 + 0] * H + offy - 0.5f;
        const float xf = floorf(x), yf = floorf(y);
        const int x0 = (int)xf, y0 = (int)yf;
        const float lx = x - xf, ly = y - yf;
        const bool xv0 = (x0 >= 0) & (x0 < W), xv1 = (x0 + 1 >= 0) & (x0 + 1 < W);
        const bool yv0 = (y0 >= 0) & (y0 < H), yv1 = (y0 + 1 >= 0) & (y0 + 1 < H);
        const int xc0 = min(max(x0, 0), W - 1), xc1 = min(max(x0 + 1, 0), W - 1);
        const int yc0 = min(max(y0, 0), H - 1), yc1 = min(max(y0 + 1, 0), H - 1);
        ti[q][s][0] = (unsigned short)(S + yc0 * W + xc0);
        ti[q][s][1] = (unsigned short)(S + yc0 * W + xc1);
        ti[q][s][2] = (unsigned short)(S + yc1 * W + xc0);
        ti[q][s][3] = (unsigned short)(S + yc1 * W + xc1);
        tw[q][s][0] = (yv0 & xv0) ? aw * (1.f - ly) * (1.f - lx) : 0.f;
        tw[q][s][1] = (yv0 & xv1) ? aw * (1.f - ly) * lx : 0.f;
        tw[q][s][2] = (yv1 & xv0) ? aw * ly * (1.f - lx) : 0.f;
        tw[q][s][3] = (yv1 & xv1) ? aw * ly * lx : 0.f;
      }
    }
  }
  __syncthreads();

  // gather + weighted sum: wave w -> queries qbase + 2w + {0,1}
  {
    const int w = t >> 6, lane = t & 63;
    const int q = w * 2 + (lane >> 5);
    const int h = (lane >> 2) & 7, cg = lane & 3;
    const int bq = qbase + q;
    const bool qv = bq < MTOT;
    const int bqc = qv ? bq : 0;
    const char* __restrict__ vb =
        (const char*)value16 + (size_t)(bqc / LQn) * ((size_t)LQn * 512);
    const unsigned laneoff = (unsigned)h * (LQn * 64u) + (unsigned)cg * 16u;

    float a0 = 0.f, a1 = 0.f, a2 = 0.f, a3 = 0.f;
    float a4 = 0.f, a5 = 0.f, a6 = 0.f, a7 = 0.f;
#pragma unroll
    for (int p = 0; p < 12; p++) {
      const int slot = p * 8 + h;
      const ushort4 tiv = *(const ushort4*)(&ti[q][slot][0]);
      const f32x4 wv = *(const f32x4*)(&tw[q][slot][0]);
#pragma unroll
      for (int k = 0; k < 4; k++) {
        const unsigned pix =
            (k == 0) ? tiv.x : (k == 1) ? tiv.y : (k == 2) ? tiv.z : tiv.w;
        const float wgt = wv[k];
        const uint4 u = *(const uint4*)(vb + ((pix << 6) + laneoff));
        a0 += wgt * __uint_as_float(u.x << 16);
        a1 += wgt * __uint_as_float(u.x & 0xffff0000u);
        a2 += wgt * __uint_as_float(u.y << 16);
        a3 += wgt * __uint_as_float(u.y & 0xffff0000u);
        a4 += wgt * __uint_as_float(u.z << 16);
        a5 += wgt * __uint_as_float(u.z & 0xffff0000u);
        a6 += wgt * __uint_as_float(u.w << 16);
        a7 += wgt * __uint_as_float(u.w & 0xffff0000u);
      }
    }
    if (qv) {
      uint4 o;
      o.x = (unsigned)f2bf(a0) | ((unsigned)f2bf(a1) << 16);
      o.y = (unsigned)f2bf(a2) | ((unsigned)f2bf(a3) << 16);
      o.z = (unsigned)f2bf(a4) | ((unsigned)f2bf(a5) << 16);
      o.w = (unsigned)f2bf(a6) | ((unsigned)f2bf(a7) << 16);
      *(uint4*)(sampled + (size_t)bq * 256 + h * 32 + cg * 8) = o;
    }
  }
}

// ---------------- host launch ----------------
extern "C" void kernel_launch(void* const* d_in, const int* in_sizes, int n_in,
                              void* d_out, int out_size, void* d_ws, size_t ws_size,
                              hipStream_t stream) {
  const float* query      = (const float*)d_in[0];
  const float* refp       = (const float*)d_in[1];
  const float* value_flat = (const float*)d_in[2];
  const float* W_val      = (const float*)d_in[3];
  const float* b_val      = (const float*)d_in[4];
  const float* W_off      = (const float*)d_in[5];
  const float* b_off      = (const float*)d_in[6];
  const float* W_attn     = (const float*)d_in[7];
  const float* b_attn     = (const float*)d_in[8];
  const float* W_out      = (const float*)d_in[9];
  const float* b_out      = (const float*)d_in[10];

  char* w = (char*)d_ws;
  size_t o = 0;
  auto carve = [&](size_t bytes) -> void* {
    void* p = (void*)(w + o);
    o += (bytes + 255) & ~(size_t)255;
    return p;
  };
  unsigned short* Wval_t  = (unsigned short*)carve(256 * 256 * 2);
  unsigned short* Wcat_t  = (unsigned short*)carve(288 * 256 * 2);
  unsigned short* Wout_t  = (unsigned short*)carve(256 * 256 * 2);
  float*          bcat    = (float*)carve(288 * 4);
  unsigned short* value16 = (unsigned short*)carve((size_t)MTOT * 256 * 2);
  float*          logits  = (float*)carve((size_t)MTOT * 288 * 4);
  unsigned short* samp_bf = (unsigned short*)carve((size_t)MTOT * 256 * 2);

  prep_weights<<<288, 256, 0, stream>>>(W_val, W_off, W_attn, W_out, b_off, b_attn,
                                        Wval_t, Wcat_t, Wout_t, bcat);

  const int mg = (MTOT + 63) / 64;               // 348
  dim3 g12(mg, 2);                               // y=0 value proj, y=1 logits proj
  gemm_fused12b<<<g12, 256, 0, stream>>>(value_flat, query, Wval_t, Wcat_t,
                                         b_val, bcat, value16, logits);

  const int sgrid = (MTOT + 7) / 8;              // 2778
  msda_sample5<<<sgrid, 256, 0, stream>>>(value16, logits, refp, samp_bf);

  gemm_a16b<<<mg, 256, 0, stream>>>(samp_bf, Wout_t, b_out, (float*)d_out);
}